// Round 8
// baseline (41.348 us; speedup 1.0000x reference)
//
#include <hip/hip_runtime.h>
#include <math.h>

// DISTANA fused prediction-kernel step.
// B=128, N=4096, IN=9, PRE=4, CELLS=16, OUT=9.
// Outputs: y (B,N,9) | new_h (B,N,16) | new_cell (B,N,16), f32 concat.
//
// R8 = R7 (quad-cooperative, 4 lanes/node, 8192 blocks = 4 wave-fills;
// confirmed +27%: occ 36->66%, 33.4us) with:
//  1. DPP quad-perm butterflies instead of ds_swizzle (VALU-only reduction,
//     removes ~480 cyc of LDS-pipe round trips from the dependent chain)
//  2. NT stores for y/new_h/new_cell (never re-read; protect L3-resident reads)
//  3. x issued before h/c (x is the deepest dependency: pre->net->cell->y)
//  4. balanced 3/3/3 y-store, constant indices (no runtime-indexed arrays)
//  5. clamp-free tanh where input provably bounded (cell net<=7, |nc|<=6, y<=4)

#define NNODES 524288
#define IN_DIM 9
#define CELLS 16
#define OUT_DIM 9
#define TPB 256
#define NPB 64               // nodes per block (4 lanes/node)
#define NBLK (NNODES / NPB)  // 8192, divisible by 8
#define NXCD 8

typedef float f32x4 __attribute__((ext_vector_type(4)));

__device__ __forceinline__ float fast_rcp(float x) {
    return __builtin_amdgcn_rcpf(x);
}

__device__ __forceinline__ float tanh_nc(float x) {
    // no clamp: caller guarantees |x| << 44 (exp argument < 88, no overflow)
    float e = __expf(2.f * x);
    return (e - 1.f) * fast_rcp(e + 1.f);
}

__device__ __forceinline__ float fast_tanh(float x) {
    return tanh_nc(fminf(fmaxf(x, -15.f), 15.f));
}

// quad butterfly sum via DPP quad_perm: xor1 = [1,0,3,2] = 0xB1,
// xor2 = [2,3,0,1] = 0x4E. Pure VALU (mov_dpp + add), no LDS pipe.
__device__ __forceinline__ float qsum(float v) {
    int a = __builtin_amdgcn_update_dpp(0, __float_as_int(v), 0xB1, 0xF, 0xF, true);
    v += __int_as_float(a);
    int b = __builtin_amdgcn_update_dpp(0, __float_as_int(v), 0x4E, 0xF, 0xF, true);
    v += __int_as_float(b);
    return v;
}

__global__ __launch_bounds__(TPB) void distana_quad_kernel(
    const float* __restrict__ input,      // (B,N,9)
    const float* __restrict__ w_pre,      // (9,4)
    const float* __restrict__ w_lstm,     // (4,16)
    const float* __restrict__ w_post,     // (16,9)
    const float* __restrict__ old_h,      // (B,N,16)
    const float* __restrict__ old_cell,   // (B,N,16)
    float* __restrict__ y,                // (B,N,9)
    float* __restrict__ new_h,            // (B,N,16)
    float* __restrict__ new_cell)         // (B,N,16)
{
    __shared__ float sWpre[64];   // (16 rows x 4), rows 9..15 zeroed
    __shared__ float sWl[64];     // (4,16)
    __shared__ float sWp[144];    // (16,9)

    const int t   = threadIdx.x;
    const int bid = blockIdx.x;
    // bijective XCD swizzle: contiguous tile range per XCD (8192 % 8 == 0)
    const int swz  = (bid & (NXCD - 1)) * (NBLK / NXCD) + (bid >> 3);
    const int node = swz * NPB + (t >> 2);
    const int sub  = t & 3;

    // ---- weight loads first (they gate the barrier; x/h/c stay in flight) ----
    if (t < 64)  sWpre[t] = (t < 36) ? w_pre[t] : 0.f;
    if (t < 64)  sWl[t]   = w_lstm[t];
    if (t < 144) sWp[t]   = w_post[t];

    // ---- x first (deepest dependency), then h/c ----
    const float* xp = input + (size_t)node * IN_DIM;
    f32x4 xl = {0.f, 0.f, 0.f, 0.f};      // this lane's x slice (zero-padded)
    if (sub == 0)      { xl[0] = xp[0]; xl[1] = xp[1]; xl[2] = xp[2]; xl[3] = xp[3]; }
    else if (sub == 1) { xl[0] = xp[4]; xl[1] = xp[5]; xl[2] = xp[6]; xl[3] = xp[7]; }
    else if (sub == 2) { xl[0] = xp[8]; }

    const float* hp = old_h    + (size_t)node * CELLS + sub * 4;
    const float* cp = old_cell + (size_t)node * CELLS + sub * 4;
    f32x4 h = *(const f32x4*)hp;          // wave: 16 nodes x 64B contiguous
    f32x4 c = *(const f32x4*)cp;

    __syncthreads();

    // ---- pre = tanh(x @ W_pre): per-lane partial dot + DPP butterfly ----
    float pre[4];
    #pragma unroll
    for (int p = 0; p < 4; ++p) {
        float s = 0.f;
        #pragma unroll
        for (int k = 0; k < 4; ++k)
            s = fmaf(xl[k], sWpre[(sub * 4 + k) * 4 + p], s);
        pre[p] = fast_tanh(qsum(s));      // x unbounded -> keep clamp
    }

    // ---- CIFG cell: this lane owns cells sub*4 .. sub*4+3 ----
    // net = oh + pre.w: |oh|<~6, |pre.w|<=1 -> |net|<=7, exp safe unclamped
    f32x4 nh, nc;
    #pragma unroll
    for (int j = 0; j < 4; ++j) {
        const int cc = sub * 4 + j;
        float s = h[j];
        #pragma unroll
        for (int p = 0; p < 4; ++p)
            s = fmaf(pre[p], sWl[p * CELLS + cc], s);
        float e  = __expf(s);                 // e^net
        float e2 = e * e;                     // e^{2 net}
        float a  = 1.f + e;
        float b  = 1.f + e2;
        float r  = fast_rcp(a * b);           // one rcp for both gates
        float ig = e * b * r;                 // sigmoid(net)
        float g  = (e2 - 1.f) * a * r;        // tanh(net)
        float v  = fmaf(ig, g - c[j], c[j]);  // (1-i)*oc + i*g
        nc[j] = v;
        nh[j] = tanh_nc(v);                   // |v| <= max(|oc|,1) <= ~6
    }
    __builtin_nontemporal_store(nh, (f32x4*)(new_h    + (size_t)node * CELLS + sub * 4));
    __builtin_nontemporal_store(nc, (f32x4*)(new_cell + (size_t)node * CELLS + sub * 4));

    // ---- y = tanh(new_h @ W_post): partial over own 4 cells + butterfly ----
    float py[OUT_DIM];
    #pragma unroll
    for (int o = 0; o < OUT_DIM; ++o) {
        float s = 0.f;
        #pragma unroll
        for (int j = 0; j < 4; ++j)
            s = fmaf(nh[j], sWp[(sub * 4 + j) * OUT_DIM + o], s);
        py[o] = qsum(s);                  // |y pre-act| <= 16*0.25 = 4
    }
    // balanced 3/3/3 store, constant indices (avoid runtime-indexed scratch)
    float* yo = y + (size_t)node * OUT_DIM;
    if (sub == 0) {
        __builtin_nontemporal_store(tanh_nc(py[0]), yo + 0);
        __builtin_nontemporal_store(tanh_nc(py[1]), yo + 1);
        __builtin_nontemporal_store(tanh_nc(py[2]), yo + 2);
    } else if (sub == 1) {
        __builtin_nontemporal_store(tanh_nc(py[3]), yo + 3);
        __builtin_nontemporal_store(tanh_nc(py[4]), yo + 4);
        __builtin_nontemporal_store(tanh_nc(py[5]), yo + 5);
    } else if (sub == 2) {
        __builtin_nontemporal_store(tanh_nc(py[6]), yo + 6);
        __builtin_nontemporal_store(tanh_nc(py[7]), yo + 7);
        __builtin_nontemporal_store(tanh_nc(py[8]), yo + 8);
    }
}

extern "C" void kernel_launch(void* const* d_in, const int* in_sizes, int n_in,
                              void* d_out, int out_size, void* d_ws, size_t ws_size,
                              hipStream_t stream) {
    const float* input    = (const float*)d_in[0];  // (B,N,9,1)
    const float* w_pre    = (const float*)d_in[1];  // (9,4)
    const float* w_lstm   = (const float*)d_in[2];  // (4,16)
    const float* w_post   = (const float*)d_in[3];  // (16,9)
    const float* old_h    = (const float*)d_in[4];  // (B,N,16)
    const float* old_cell = (const float*)d_in[5];  // (B,N,16)

    float* out = (float*)d_out;
    float* yp       = out;                                    // B*N*9
    float* new_h    = out + (size_t)NNODES * OUT_DIM;         // B*N*16
    float* new_cell = new_h + (size_t)NNODES * CELLS;         // B*N*16

    dim3 grid(NBLK), block(TPB);
    distana_quad_kernel<<<grid, block, 0, stream>>>(
        input, w_pre, w_lstm, w_post, old_h, old_cell, yp, new_h, new_cell);
}

// Round 9
// 31.389 us; speedup vs baseline: 1.3173x; 1.3173x over previous
//
#include <hip/hip_runtime.h>
#include <math.h>

// DISTANA fused prediction-kernel step.
// B=128, N=4096, IN=9, PRE=4, CELLS=16, OUT=9.
// Outputs: y (B,N,9) | new_h (B,N,16) | new_cell (B,N,16), f32 concat.
//
// R9 = R8 minus NT stores (R8's regression: NT bypassed L2 write-coalescing,
// scalar y-stores amplified WRITE_SIZE 84->112 MB, +8us). Keeps from R8:
//  - DPP quad-perm butterflies (VALU-only reduction; VALUBusy 32->23%)
//  - x issued before h/c (deepest dependency)
//  - balanced 3/3/3 y-store, constant indices
//  - clamp-free tanh on bounded paths
// Base: R7 quad-cooperative (4 lanes/node, 8192 blocks, occ 66%, 33.4us).

#define NNODES 524288
#define IN_DIM 9
#define CELLS 16
#define OUT_DIM 9
#define TPB 256
#define NPB 64               // nodes per block (4 lanes/node)
#define NBLK (NNODES / NPB)  // 8192, divisible by 8
#define NXCD 8

typedef float f32x4 __attribute__((ext_vector_type(4)));

__device__ __forceinline__ float fast_rcp(float x) {
    return __builtin_amdgcn_rcpf(x);
}

__device__ __forceinline__ float tanh_nc(float x) {
    // no clamp: caller guarantees |x| << 44 (exp argument < 88, no overflow)
    float e = __expf(2.f * x);
    return (e - 1.f) * fast_rcp(e + 1.f);
}

__device__ __forceinline__ float fast_tanh(float x) {
    return tanh_nc(fminf(fmaxf(x, -15.f), 15.f));
}

// quad butterfly sum via DPP quad_perm: xor1 = [1,0,3,2] = 0xB1,
// xor2 = [2,3,0,1] = 0x4E. Pure VALU (mov_dpp + add), no LDS pipe.
__device__ __forceinline__ float qsum(float v) {
    int a = __builtin_amdgcn_update_dpp(0, __float_as_int(v), 0xB1, 0xF, 0xF, true);
    v += __int_as_float(a);
    int b = __builtin_amdgcn_update_dpp(0, __float_as_int(v), 0x4E, 0xF, 0xF, true);
    v += __int_as_float(b);
    return v;
}

__global__ __launch_bounds__(TPB) void distana_quad_kernel(
    const float* __restrict__ input,      // (B,N,9)
    const float* __restrict__ w_pre,      // (9,4)
    const float* __restrict__ w_lstm,     // (4,16)
    const float* __restrict__ w_post,     // (16,9)
    const float* __restrict__ old_h,      // (B,N,16)
    const float* __restrict__ old_cell,   // (B,N,16)
    float* __restrict__ y,                // (B,N,9)
    float* __restrict__ new_h,            // (B,N,16)
    float* __restrict__ new_cell)         // (B,N,16)
{
    __shared__ float sWpre[64];   // (16 rows x 4), rows 9..15 zeroed
    __shared__ float sWl[64];     // (4,16)
    __shared__ float sWp[144];    // (16,9)

    const int t   = threadIdx.x;
    const int bid = blockIdx.x;
    // bijective XCD swizzle: contiguous tile range per XCD (8192 % 8 == 0)
    const int swz  = (bid & (NXCD - 1)) * (NBLK / NXCD) + (bid >> 3);
    const int node = swz * NPB + (t >> 2);
    const int sub  = t & 3;

    // ---- weight loads first (they gate the barrier; x/h/c stay in flight) ----
    if (t < 64)  sWpre[t] = (t < 36) ? w_pre[t] : 0.f;
    if (t < 64)  sWl[t]   = w_lstm[t];
    if (t < 144) sWp[t]   = w_post[t];

    // ---- x first (deepest dependency), then h/c ----
    const float* xp = input + (size_t)node * IN_DIM;
    f32x4 xl = {0.f, 0.f, 0.f, 0.f};      // this lane's x slice (zero-padded)
    if (sub == 0)      { xl[0] = xp[0]; xl[1] = xp[1]; xl[2] = xp[2]; xl[3] = xp[3]; }
    else if (sub == 1) { xl[0] = xp[4]; xl[1] = xp[5]; xl[2] = xp[6]; xl[3] = xp[7]; }
    else if (sub == 2) { xl[0] = xp[8]; }

    const float* hp = old_h    + (size_t)node * CELLS + sub * 4;
    const float* cp = old_cell + (size_t)node * CELLS + sub * 4;
    f32x4 h = *(const f32x4*)hp;          // wave: 16 nodes x 64B contiguous
    f32x4 c = *(const f32x4*)cp;

    __syncthreads();

    // ---- pre = tanh(x @ W_pre): per-lane partial dot + DPP butterfly ----
    float pre[4];
    #pragma unroll
    for (int p = 0; p < 4; ++p) {
        float s = 0.f;
        #pragma unroll
        for (int k = 0; k < 4; ++k)
            s = fmaf(xl[k], sWpre[(sub * 4 + k) * 4 + p], s);
        pre[p] = fast_tanh(qsum(s));      // x unbounded -> keep clamp
    }

    // ---- CIFG cell: this lane owns cells sub*4 .. sub*4+3 ----
    // net = oh + pre.w: |oh|<~6, |pre.w|<=1 -> |net|<=7, exp safe unclamped
    f32x4 nh, nc;
    #pragma unroll
    for (int j = 0; j < 4; ++j) {
        const int cc = sub * 4 + j;
        float s = h[j];
        #pragma unroll
        for (int p = 0; p < 4; ++p)
            s = fmaf(pre[p], sWl[p * CELLS + cc], s);
        float e  = __expf(s);                 // e^net
        float e2 = e * e;                     // e^{2 net}
        float a  = 1.f + e;
        float b  = 1.f + e2;
        float r  = fast_rcp(a * b);           // one rcp for both gates
        float ig = e * b * r;                 // sigmoid(net)
        float g  = (e2 - 1.f) * a * r;        // tanh(net)
        float v  = fmaf(ig, g - c[j], c[j]);  // (1-i)*oc + i*g
        nc[j] = v;
        nh[j] = tanh_nc(v);                   // |v| <= max(|oc|,1) <= ~6
    }
    *(f32x4*)(new_h    + (size_t)node * CELLS + sub * 4) = nh;
    *(f32x4*)(new_cell + (size_t)node * CELLS + sub * 4) = nc;

    // ---- y = tanh(new_h @ W_post): partial over own 4 cells + butterfly ----
    float py[OUT_DIM];
    #pragma unroll
    for (int o = 0; o < OUT_DIM; ++o) {
        float s = 0.f;
        #pragma unroll
        for (int j = 0; j < 4; ++j)
            s = fmaf(nh[j], sWp[(sub * 4 + j) * OUT_DIM + o], s);
        py[o] = qsum(s);                  // |y pre-act| <= 16*0.25 = 4
    }
    // balanced 3/3/3 store, constant indices (avoid runtime-indexed scratch)
    float* yo = y + (size_t)node * OUT_DIM;
    if (sub == 0) {
        yo[0] = tanh_nc(py[0]);
        yo[1] = tanh_nc(py[1]);
        yo[2] = tanh_nc(py[2]);
    } else if (sub == 1) {
        yo[3] = tanh_nc(py[3]);
        yo[4] = tanh_nc(py[4]);
        yo[5] = tanh_nc(py[5]);
    } else if (sub == 2) {
        yo[6] = tanh_nc(py[6]);
        yo[7] = tanh_nc(py[7]);
        yo[8] = tanh_nc(py[8]);
    }
}

extern "C" void kernel_launch(void* const* d_in, const int* in_sizes, int n_in,
                              void* d_out, int out_size, void* d_ws, size_t ws_size,
                              hipStream_t stream) {
    const float* input    = (const float*)d_in[0];  // (B,N,9,1)
    const float* w_pre    = (const float*)d_in[1];  // (9,4)
    const float* w_lstm   = (const float*)d_in[2];  // (4,16)
    const float* w_post   = (const float*)d_in[3];  // (16,9)
    const float* old_h    = (const float*)d_in[4];  // (B,N,16)
    const float* old_cell = (const float*)d_in[5];  // (B,N,16)

    float* out = (float*)d_out;
    float* yp       = out;                                    // B*N*9
    float* new_h    = out + (size_t)NNODES * OUT_DIM;         // B*N*16
    float* new_cell = new_h + (size_t)NNODES * CELLS;         // B*N*16

    dim3 grid(NBLK), block(TPB);
    distana_quad_kernel<<<grid, block, 0, stream>>>(
        input, w_pre, w_lstm, w_post, old_h, old_cell, yp, new_h, new_cell);
}